// Round 9
// baseline (365.237 us; speedup 1.0000x reference)
//
#include <hip/hip_runtime.h>
#include <hip/hip_bf16.h>

#define D 64

typedef __attribute__((ext_vector_type(8))) _Float16 half8;
typedef __attribute__((ext_vector_type(4))) float floatx4;

// ---- k_pre: fp16 convert + per-row sq + block partial sum(z^2) + block column sums ----
__global__ __launch_bounds__(256) void k_pre(const float* __restrict__ x, const float* __restrict__ y,
                                             int nx, _Float16* __restrict__ zh,
                                             float* __restrict__ sq, double* __restrict__ Tpart,
                                             float* __restrict__ Spart) {
    int tid = threadIdx.x;
    int lane = tid & 63, wid = tid >> 6;
    int t = blockIdx.x * 256 + tid;             // 8 elements per thread; block = 32 rows
    size_t e = (size_t)t * 8;
    int row = (int)(e >> 6);
    const float* src = (row < nx) ? (x + e) : (y + (e - (size_t)nx * D));
    float4 v0 = ((const float4*)src)[0];
    float4 v1 = ((const float4*)src)[1];
    half8 h;
    h[0]=(_Float16)v0.x; h[1]=(_Float16)v0.y; h[2]=(_Float16)v0.z; h[3]=(_Float16)v0.w;
    h[4]=(_Float16)v1.x; h[5]=(_Float16)v1.y; h[6]=(_Float16)v1.z; h[7]=(_Float16)v1.w;
    *(half8*)(zh + e) = h;
    float p = v0.x*v0.x + v0.y*v0.y + v0.z*v0.z + v0.w*v0.w
            + v1.x*v1.x + v1.y*v1.y + v1.z*v1.z + v1.w*v1.w;
    float s = p;
    s += __shfl_xor(s, 1);
    s += __shfl_xor(s, 2);
    s += __shfl_xor(s, 4);
    if ((tid & 7) == 0) sq[row] = s;

    __shared__ float colbuf[32][64];
    int rib = tid >> 3, cg = tid & 7;
    *(float4*)&colbuf[rib][cg * 8]     = v0;
    *(float4*)&colbuf[rib][cg * 8 + 4] = v1;

    double dp = (double)p;
    dp += __shfl_xor(dp, 1);
    dp += __shfl_xor(dp, 2);
    dp += __shfl_xor(dp, 4);
    dp += __shfl_xor(dp, 8);
    dp += __shfl_xor(dp, 16);
    dp += __shfl_xor(dp, 32);
    __shared__ double redw[4];
    if (lane == 0) redw[wid] = dp;
    __syncthreads();
    if (tid == 0) Tpart[blockIdx.x] = (redw[0] + redw[1]) + (redw[2] + redw[3]);

    if (tid < 64) {
        float cs = 0.f;
#pragma unroll
        for (int r2 = 0; r2 < 32; ++r2) cs += colbuf[r2][tid];
        Spart[blockIdx.x * 64 + tid] = cs;
    }
}

// ---- k_bw: reduce Tpart/Spart -> cq = log2e/(4*bw) ----
__global__ __launch_bounds__(256) void k_bw(const double* __restrict__ Tpart, int ntp,
                                            const float* __restrict__ Spart, int nsp,
                                            int N, float* __restrict__ cq_p) {
    int t = threadIdx.x;
    double Tp = 0.0;
    for (int b = t; b < ntp; b += 256) Tp += Tpart[b];

    int q = t >> 6, col = t & 63;
    int bpq = nsp >> 2;
    const float* sp = Spart + (size_t)(q * bpq) * 64 + col;
    float c0 = 0.f, c1 = 0.f, c2 = 0.f, c3 = 0.f;
    for (int b = 0; b < bpq; b += 4) {
        c0 += sp[(b + 0) * 64];
        c1 += sp[(b + 1) * 64];
        c2 += sp[(b + 2) * 64];
        c3 += sp[(b + 3) * 64];
    }
    __shared__ float cred[256];
    cred[t] = (c0 + c1) + (c2 + c3);

    __shared__ double red[256];
    red[t] = Tp;
    __syncthreads();
    for (int off = 128; off > 0; off >>= 1) {
        if (t < off) red[t] += red[t + off];
        __syncthreads();
    }
    double T = red[0];
    __shared__ double red2[64];
    if (t < 64) {
        float Sk = cred[t] + cred[t + 64] + cred[t + 128] + cred[t + 192];
        red2[t] = (double)Sk * (double)Sk;
    }
    __syncthreads();
    if (t == 0) {
        double S2 = 0.0;
        for (int i = 0; i < 64; ++i) S2 += red2[i];
        double sumd2 = 2.0 * (double)N * T - 2.0 * S2;
        double bw = sumd2 / ((double)N * (double)N - (double)N);
        cq_p[0] = (float)(1.4426950408889634 / (4.0 * bw));
    }
}

// ---- k_mmd<V>: ablation variants of the triangle pairwise pass ----
// V0: full (real output).  V1: loads+MFMA, no epilogue.  V2: loads only.
// V3: full compute, B-loads wrapped to 4KB L1-window.
template<int V>
__global__ __launch_bounds__(256, 4) void k_mmd(const _Float16* __restrict__ zh,
                                                const float* __restrict__ sq,
                                                const float* __restrict__ cq_p,
                                                int nb, double* __restrict__ partial) {
    int bid = (nb - 1) - (int)blockIdx.x;       // longest blocks first
    int g = (int)((sqrtf(1.0f + 2.0f * (float)bid) - 1.0f) * 0.5f);
    while (2 * (g + 1) * (g + 2) <= bid) ++g;
    while (2 * g * (g + 1) > bid) --g;
    int r = bid - 2 * g * (g + 1);
    int gp1 = g + 1;
    int rig = r / gp1;
    int jc  = r - rig * gp1;
    int ib  = 4 * g + rig;

    int jstart = jc * 512;
    int jend   = (ib + 1) * 128;
    if (jend > jstart + 512) jend = jstart + 512;
    int njt = (jend - jstart) >> 4;             // in {8,16,24,32}
    int diag_j = ib * 128;

    int lane = threadIdx.x & 63;
    int wid  = threadIdx.x >> 6;
    int i0 = ib * 128 + wid * 32;

    float cq  = cq_p[0];
    float c2q = 2.0f * cq;

    int lrow = lane & 15;
    int kb = (lane >> 4) * 8;

    const _Float16* ar0 = zh + (size_t)(i0 + lrow) * D + kb;
    half8 a00 = *(const half8*)(ar0);
    half8 a01 = *(const half8*)(ar0 + 32);
    half8 a10 = *(const half8*)(ar0 + 16 * D);
    half8 a11 = *(const half8*)(ar0 + 16 * D + 32);

    int irh = (lane >> 4) * 4;
    float nai0[4], nai1[4];
#pragma unroll
    for (int rr = 0; rr < 4; ++rr) {
        nai0[rr] = -sq[i0 + irh + rr] * cq;
        nai1[rr] = -sq[i0 + 16 + irh + rr] * cq;
    }

    const _Float16* bptr = zh + (size_t)(jstart + lrow) * D + kb;
    const float* sqjp = sq + jstart + lrow;

    float acc = 0.f;
    int jcur = jstart;

#pragma unroll 2
    for (int jt = 0; jt < njt; ++jt) {
        const _Float16* bcur;
        float sqj;
        if constexpr (V == 3) {
            bcur = bptr + (size_t)((jt & 1) * 16) * D;   // 4KB window: L1-resident
            sqj  = sqjp[(jt & 1) * 16];
        } else {
            bcur = bptr + (size_t)jt * 16 * D;
            sqj  = sqjp[jt * 16];
        }
        half8 b0 = *(const half8*)(bcur);
        half8 b1 = *(const half8*)(bcur + 32);

        if constexpr (V == 2) {
            // loads only
            acc += (float)b0[0] + (float)b1[0] + sqj;
        } else {
            floatx4 d0 = {0.f, 0.f, 0.f, 0.f};
            floatx4 d1 = {0.f, 0.f, 0.f, 0.f};
            d0 = __builtin_amdgcn_mfma_f32_16x16x32_f16(a00, b0, d0, 0, 0, 0);
            d0 = __builtin_amdgcn_mfma_f32_16x16x32_f16(a01, b1, d0, 0, 0, 0);
            d1 = __builtin_amdgcn_mfma_f32_16x16x32_f16(a10, b0, d1, 0, 0, 0);
            d1 = __builtin_amdgcn_mfma_f32_16x16x32_f16(a11, b1, d1, 0, 0, 0);
            if constexpr (V == 1) {
                // MFMA live, epilogue stubbed with cheap sum
                acc += ((d0[0] + d0[1]) + (d0[2] + d0[3]))
                     + ((d1[0] + d1[1]) + (d1[2] + d1[3])) + sqj;
            } else {
                float nbj = -sqj * cq;
                float part = 0.f;
#pragma unroll
                for (int rr = 0; rr < 4; ++rr) {
                    float u0 = fminf(fmaf(d0[rr], c2q, nai0[rr] + nbj), 0.f);
                    float u1 = fminf(fmaf(d1[rr], c2q, nai1[rr] + nbj), 0.f);
                    float q0 = __builtin_amdgcn_exp2f(u0);
                    float q1 = __builtin_amdgcn_exp2f(u1);
                    float m01 = q0 * q0,   m11 = q1 * q1;     // Eq^2
                    float m02 = m01 * m01, m12 = m11 * m11;   // Eq^4
                    float m03 = m02 * m02, m13 = m12 * m12;   // Eq^8
                    float s0 = (q0 + m01) + (m02 + m03);
                    float s1 = (q1 + m11) + (m12 + m13);
                    part += fmaf(m03, m03, s0) + fmaf(m13, m13, s1);  // + Eq^16
                }
                float wf = (jcur >= diag_j) ? 1.0f : 2.0f;
                acc = fmaf(part, wf, acc);
            }
        }
        jcur += 16;
    }

    // wave reduce (f64), then tiny LDS combine across the 4 waves
    double wacc = (double)acc;
    wacc += __shfl_xor(wacc, 1);
    wacc += __shfl_xor(wacc, 2);
    wacc += __shfl_xor(wacc, 4);
    wacc += __shfl_xor(wacc, 8);
    wacc += __shfl_xor(wacc, 16);
    wacc += __shfl_xor(wacc, 32);
    __shared__ double redw[4];
    if (lane == 0) redw[wid] = wacc;
    __syncthreads();
    if (threadIdx.x == 0) partial[bid] = (redw[0] + redw[1]) + (redw[2] + redw[3]);
}

// ---- k_final: classify weighted partials into XX/XY/YY, finalize ----
__global__ __launch_bounds__(256) void k_final(const double* __restrict__ partial, int nb,
                                               int nxTile, int nxChunk,
                                               int nx, int ny, float* __restrict__ out) {
    int t = threadIdx.x;
    double sXX = 0.0, sXY = 0.0, sYY = 0.0;
    for (int p = t; p < nb; p += 256) {
        int g = (int)((sqrtf(1.0f + 2.0f * (float)p) - 1.0f) * 0.5f);
        while (2 * (g + 1) * (g + 2) <= p) ++g;
        while (2 * g * (g + 1) > p) --g;
        int r = p - 2 * g * (g + 1);
        int gp1 = g + 1;
        int rig = r / gp1;
        int jc  = r - rig * gp1;
        int ib  = 4 * g + rig;
        double v = partial[p];
        bool iX = ib < nxTile;
        bool jX = jc < nxChunk;
        if (iX && jX) sXX += v;
        else if (iX != jX) sXY += v;
        else sYY += v;
    }
    __shared__ double r0[256], r1[256], r2[256];
    r0[t] = sXX; r1[t] = sXY; r2[t] = sYY;
    __syncthreads();
    for (int off = 128; off > 0; off >>= 1) {
        if (t < off) {
            r0[t] += r0[t + off];
            r1[t] += r1[t + off];
            r2[t] += r2[t + off];
        }
        __syncthreads();
    }
    if (t == 0) {
        double XX = r0[0] / ((double)nx * (double)nx);
        double XY = r1[0] / (2.0 * (double)nx * (double)ny);
        double YY = r2[0] / ((double)ny * (double)ny);
        out[0] = (float)(XX - 2.0 * XY + YY);
    }
}

extern "C" void kernel_launch(void* const* d_in, const int* in_sizes, int n_in,
                              void* d_out, int out_size, void* d_ws, size_t ws_size,
                              hipStream_t stream) {
    const float* x = (const float*)d_in[0];
    const float* y = (const float*)d_in[1];
    float* out = (float*)d_out;

    int nx = in_sizes[0] / D;     // 8192
    int ny = in_sizes[1] / D;     // 8192
    int N  = nx + ny;             // 16384

    int pre_blocks = (N * D / 8) / 256;    // 512 (32 rows per block)
    int nT = N / 128;                      // 128 i-tiles
    int ngr = nT / 4;                      // 32 row groups
    int nb = 2 * ngr * (ngr + 1);          // 2112 triangle chunk-blocks
    int nxTile = nx / 128;                 // 64
    int nxChunk = nx / 512;                // 16

    // workspace layout
    char* w = (char*)d_ws;
    double* Tpart   = (double*)(w + 0);        // 512*8    = 4096          -> 4096
    double* partial = (double*)(w + 4096);     // 2112*8   = 16896         -> 20992
    float*  Spart   = (float*) (w + 20992);    // 512*64*4 = 131072        -> 152064
    float*  sq      = (float*) (w + 152064);   // N*4      = 65536         -> 217600
    float*  cq      = (float*) (w + 217600);   // 64 B pad                 -> 217664
    _Float16* zh    = (_Float16*)(w + 217664); // N*64*2   = 2 MiB
    // probe scratch partials: reuse Spart's region (consumed by k_bw before probes run)
    double* part1   = (double*)(w + 20992);
    double* part2   = (double*)(w + 37888);
    double* part3   = (double*)(w + 54784);

    k_pre    <<<pre_blocks, 256, 0, stream>>>(x, y, nx, zh, sq, Tpart, Spart);
    k_bw     <<<1, 256, 0, stream>>>(Tpart, pre_blocks, Spart, pre_blocks, N, cq);
    k_mmd<0> <<<nb, 256, 0, stream>>>(zh, sq, cq, nb, partial);
    k_final  <<<1, 256, 0, stream>>>(partial, nb, nxTile, nxChunk, nx, ny, out);
    // ---- ablation probes (results unused; written to scratch) ----
    k_mmd<1> <<<nb, 256, 0, stream>>>(zh, sq, cq, nb, part1);
    k_mmd<2> <<<nb, 256, 0, stream>>>(zh, sq, cq, nb, part2);
    k_mmd<3> <<<nb, 256, 0, stream>>>(zh, sq, cq, nb, part3);
}

// Round 10
// 128.988 us; speedup vs baseline: 2.8316x; 2.8316x over previous
//
#include <hip/hip_runtime.h>
#include <hip/hip_bf16.h>

#define D 64

typedef __attribute__((ext_vector_type(8))) _Float16 half8;
typedef __attribute__((ext_vector_type(4))) float floatx4;

typedef __attribute__((address_space(1))) unsigned int gu32_t;
typedef __attribute__((address_space(3))) unsigned int lu32_t;

// ---- k_pre: fp16 convert + per-row sq + block partial sum(z^2) + block column sums ----
__global__ __launch_bounds__(256) void k_pre(const float* __restrict__ x, const float* __restrict__ y,
                                             int nx, _Float16* __restrict__ zh,
                                             float* __restrict__ sq, double* __restrict__ Tpart,
                                             float* __restrict__ Spart) {
    int tid = threadIdx.x;
    int lane = tid & 63, wid = tid >> 6;
    int t = blockIdx.x * 256 + tid;             // 8 elements per thread; block = 32 rows
    size_t e = (size_t)t * 8;
    int row = (int)(e >> 6);
    const float* src = (row < nx) ? (x + e) : (y + (e - (size_t)nx * D));
    float4 v0 = ((const float4*)src)[0];
    float4 v1 = ((const float4*)src)[1];
    half8 h;
    h[0]=(_Float16)v0.x; h[1]=(_Float16)v0.y; h[2]=(_Float16)v0.z; h[3]=(_Float16)v0.w;
    h[4]=(_Float16)v1.x; h[5]=(_Float16)v1.y; h[6]=(_Float16)v1.z; h[7]=(_Float16)v1.w;
    *(half8*)(zh + e) = h;
    float p = v0.x*v0.x + v0.y*v0.y + v0.z*v0.z + v0.w*v0.w
            + v1.x*v1.x + v1.y*v1.y + v1.z*v1.z + v1.w*v1.w;
    float s = p;
    s += __shfl_xor(s, 1);
    s += __shfl_xor(s, 2);
    s += __shfl_xor(s, 4);
    if ((tid & 7) == 0) sq[row] = s;

    __shared__ float colbuf[32][64];
    int rib = tid >> 3, cg = tid & 7;
    *(float4*)&colbuf[rib][cg * 8]     = v0;
    *(float4*)&colbuf[rib][cg * 8 + 4] = v1;

    double dp = (double)p;
    dp += __shfl_xor(dp, 1);
    dp += __shfl_xor(dp, 2);
    dp += __shfl_xor(dp, 4);
    dp += __shfl_xor(dp, 8);
    dp += __shfl_xor(dp, 16);
    dp += __shfl_xor(dp, 32);
    __shared__ double redw[4];
    if (lane == 0) redw[wid] = dp;
    __syncthreads();
    if (tid == 0) Tpart[blockIdx.x] = (redw[0] + redw[1]) + (redw[2] + redw[3]);

    if (tid < 64) {
        float cs = 0.f;
#pragma unroll
        for (int r2 = 0; r2 < 32; ++r2) cs += colbuf[r2][tid];
        Spart[blockIdx.x * 64 + tid] = cs;
    }
}

// ---- k_bw: reduce Tpart/Spart -> cq = log2e/(4*bw) ----
__global__ __launch_bounds__(256) void k_bw(const double* __restrict__ Tpart, int ntp,
                                            const float* __restrict__ Spart, int nsp,
                                            int N, float* __restrict__ cq_p) {
    int t = threadIdx.x;
    double Tp = 0.0;
    for (int b = t; b < ntp; b += 256) Tp += Tpart[b];

    int q = t >> 6, col = t & 63;
    int bpq = nsp >> 2;
    const float* sp = Spart + (size_t)(q * bpq) * 64 + col;
    float c0 = 0.f, c1 = 0.f, c2 = 0.f, c3 = 0.f;
    for (int b = 0; b < bpq; b += 4) {
        c0 += sp[(b + 0) * 64];
        c1 += sp[(b + 1) * 64];
        c2 += sp[(b + 2) * 64];
        c3 += sp[(b + 3) * 64];
    }
    __shared__ float cred[256];
    cred[t] = (c0 + c1) + (c2 + c3);

    __shared__ double red[256];
    red[t] = Tp;
    __syncthreads();
    for (int off = 128; off > 0; off >>= 1) {
        if (t < off) red[t] += red[t + off];
        __syncthreads();
    }
    double T = red[0];
    __shared__ double red2[64];
    if (t < 64) {
        float Sk = cred[t] + cred[t + 64] + cred[t + 128] + cred[t + 192];
        red2[t] = (double)Sk * (double)Sk;
    }
    __syncthreads();
    if (t == 0) {
        double S2 = 0.0;
        for (int i = 0; i < 64; ++i) S2 += red2[i];
        double sumd2 = 2.0 * (double)N * T - 2.0 * S2;
        double bw = sumd2 / ((double)N * (double)N - (double)N);
        cq_p[0] = (float)(1.4426950408889634 / (4.0 * bw));
    }
}

// ---- k_mmd: triangle pass, B staged in LDS (global_load_lds + XOR swizzle) ----
// Per block: 128 i-rows x j-chunk (<=512). LDS tile = 32 j-rows x 64 cols fp16 = 4KB,
// double-buffered. Swizzle: LDS[row][cc] holds global chunk c = cc ^ (row&7) (16B chunks);
// achieved by pre-swizzling the per-lane GLOBAL source (linear LDS dest, m173 pattern).
// m97 2-phase: STAGE(next) -> compute(cur) -> __syncthreads (drain+barrier).
__global__ __launch_bounds__(256, 6) void k_mmd(const _Float16* __restrict__ zh,
                                                const float* __restrict__ sq,
                                                const float* __restrict__ cq_p,
                                                int nb, double* __restrict__ partial) {
    int bid = (nb - 1) - (int)blockIdx.x;       // longest blocks first
    int g = (int)((sqrtf(1.0f + 2.0f * (float)bid) - 1.0f) * 0.5f);
    while (2 * (g + 1) * (g + 2) <= bid) ++g;
    while (2 * g * (g + 1) > bid) --g;
    int r = bid - 2 * g * (g + 1);
    int gp1 = g + 1;
    int rig = r / gp1;
    int jc  = r - rig * gp1;
    int ib  = 4 * g + rig;

    int jstart = jc * 512;
    int jend   = (ib + 1) * 128;
    if (jend > jstart + 512) jend = jstart + 512;
    int nt = (jend - jstart) >> 5;              // 32-j tiles: nt in {4,8,12,16}
    int diag_j = ib * 128;

    int tid  = threadIdx.x;
    int lane = tid & 63;
    int wid  = tid >> 6;
    int i0 = ib * 128 + wid * 32;

    float cq  = cq_p[0];
    float c2q = 2.0f * cq;

    int lrow = lane & 15;
    int c2   = lane >> 4;                       // chunk index 0..3 (k-base = c2*8)
    int kb   = c2 * 8;

    // A fragments (once per block)
    const _Float16* ar0 = zh + (size_t)(i0 + lrow) * D + kb;
    half8 a00 = *(const half8*)(ar0);
    half8 a01 = *(const half8*)(ar0 + 32);
    half8 a10 = *(const half8*)(ar0 + 16 * D);
    half8 a11 = *(const half8*)(ar0 + 16 * D + 32);

    int irh = c2 * 4;
    float nai0[4], nai1[4];
#pragma unroll
    for (int rr = 0; rr < 4; ++rr) {
        nai0[rr] = -sq[i0 + irh + rr] * cq;
        nai1[rr] = -sq[i0 + 16 + irh + rr] * cq;
    }

    // ---- LDS staging setup ----
    __shared__ __align__(16) _Float16 bsm[2][32 * 64];   // 2 x 4KB
    int srow = tid >> 3;                        // row within tile 0..31
    int scc  = tid & 7;                         // stored chunk slot 0..7
    int sc   = scc ^ (srow & 7);                // source chunk (involution)
    const char* zbase = (const char*)zh + (size_t)jstart * 128 + srow * 128 + sc * 16;
    char* ldsw = (char*)&bsm[0][0] + wid * 1024;   // wave-uniform dest base

    auto STAGE = [&](int buf, int tile) {
        const char* src = zbase + (size_t)tile * (32 * 128);
        __builtin_amdgcn_global_load_lds((const gu32_t*)(const void*)src,
                                         (lu32_t*)(void*)(ldsw + buf * 4096),
                                         16, 0, 0);
    };

    float acc = 0.f;

    STAGE(0, 0);
    __syncthreads();                            // drain vmcnt(0) + barrier: buf0 ready

    for (int t = 0; t < nt; ++t) {
        if (t + 1 < nt) STAGE((t + 1) & 1, t + 1);   // issue next tile early
        const char* bb = (const char*)&bsm[t & 1][0];
        int j0t = jstart + t * 32;
#pragma unroll
        for (int s = 0; s < 2; ++s) {
            int jr = s * 16 + lrow;
            int swz = jr & 7;
            half8 b0 = *(const half8*)(bb + jr * 128 + ((c2 ^ swz) * 16));
            half8 b1 = *(const half8*)(bb + jr * 128 + (((c2 + 4) ^ swz) * 16));
            float sqj = sq[j0t + s * 16 + lrow];

            floatx4 d0 = {0.f, 0.f, 0.f, 0.f};
            floatx4 d1 = {0.f, 0.f, 0.f, 0.f};
            d0 = __builtin_amdgcn_mfma_f32_16x16x32_f16(a00, b0, d0, 0, 0, 0);
            d0 = __builtin_amdgcn_mfma_f32_16x16x32_f16(a01, b1, d0, 0, 0, 0);
            d1 = __builtin_amdgcn_mfma_f32_16x16x32_f16(a10, b0, d1, 0, 0, 0);
            d1 = __builtin_amdgcn_mfma_f32_16x16x32_f16(a11, b1, d1, 0, 0, 0);

            float nbj = -sqj * cq;
            float part = 0.f;
#pragma unroll
            for (int rr = 0; rr < 4; ++rr) {
                float u0 = fminf(fmaf(d0[rr], c2q, nai0[rr] + nbj), 0.f);
                float u1 = fminf(fmaf(d1[rr], c2q, nai1[rr] + nbj), 0.f);
                float q0 = __builtin_amdgcn_exp2f(u0);
                float q1 = __builtin_amdgcn_exp2f(u1);
                float m01 = q0 * q0,   m11 = q1 * q1;     // Eq^2
                float m02 = m01 * m01, m12 = m11 * m11;   // Eq^4
                float m03 = m02 * m02, m13 = m12 * m12;   // Eq^8
                float s0 = (q0 + m01) + (m02 + m03);
                float s1 = (q1 + m11) + (m12 + m13);
                part += fmaf(m03, m03, s0) + fmaf(m13, m13, s1);  // + Eq^16
            }
            float wf = ((j0t + s * 16) >= diag_j) ? 1.0f : 2.0f;
            acc = fmaf(part, wf, acc);
        }
        __syncthreads();                        // drain vmcnt(0) (next tile landed) + protect buffer reuse
    }

    // wave reduce (f64), then tiny LDS combine across the 4 waves
    double wacc = (double)acc;
    wacc += __shfl_xor(wacc, 1);
    wacc += __shfl_xor(wacc, 2);
    wacc += __shfl_xor(wacc, 4);
    wacc += __shfl_xor(wacc, 8);
    wacc += __shfl_xor(wacc, 16);
    wacc += __shfl_xor(wacc, 32);
    __shared__ double redr[4];
    if (lane == 0) redr[wid] = wacc;
    __syncthreads();
    if (tid == 0) partial[bid] = (redr[0] + redr[1]) + (redr[2] + redr[3]);
}

// ---- k_final: classify weighted partials into XX/XY/YY, finalize ----
__global__ __launch_bounds__(256) void k_final(const double* __restrict__ partial, int nb,
                                               int nxTile, int nxChunk,
                                               int nx, int ny, float* __restrict__ out) {
    int t = threadIdx.x;
    double sXX = 0.0, sXY = 0.0, sYY = 0.0;
    for (int p = t; p < nb; p += 256) {
        int g = (int)((sqrtf(1.0f + 2.0f * (float)p) - 1.0f) * 0.5f);
        while (2 * (g + 1) * (g + 2) <= p) ++g;
        while (2 * g * (g + 1) > p) --g;
        int r = p - 2 * g * (g + 1);
        int gp1 = g + 1;
        int rig = r / gp1;
        int jc  = r - rig * gp1;
        int ib  = 4 * g + rig;
        double v = partial[p];
        bool iX = ib < nxTile;
        bool jX = jc < nxChunk;
        if (iX && jX) sXX += v;
        else if (iX != jX) sXY += v;
        else sYY += v;
    }
    __shared__ double r0[256], r1[256], r2[256];
    r0[t] = sXX; r1[t] = sXY; r2[t] = sYY;
    __syncthreads();
    for (int off = 128; off > 0; off >>= 1) {
        if (t < off) {
            r0[t] += r0[t + off];
            r1[t] += r1[t + off];
            r2[t] += r2[t + off];
        }
        __syncthreads();
    }
    if (t == 0) {
        double XX = r0[0] / ((double)nx * (double)nx);
        double XY = r1[0] / (2.0 * (double)nx * (double)ny);
        double YY = r2[0] / ((double)ny * (double)ny);
        out[0] = (float)(XX - 2.0 * XY + YY);
    }
}

extern "C" void kernel_launch(void* const* d_in, const int* in_sizes, int n_in,
                              void* d_out, int out_size, void* d_ws, size_t ws_size,
                              hipStream_t stream) {
    const float* x = (const float*)d_in[0];
    const float* y = (const float*)d_in[1];
    float* out = (float*)d_out;

    int nx = in_sizes[0] / D;     // 8192
    int ny = in_sizes[1] / D;     // 8192
    int N  = nx + ny;             // 16384

    int pre_blocks = (N * D / 8) / 256;    // 512 (32 rows per block)
    int nT = N / 128;                      // 128 i-tiles
    int ngr = nT / 4;                      // 32 row groups
    int nb = 2 * ngr * (ngr + 1);          // 2112 triangle chunk-blocks
    int nxTile = nx / 128;                 // 64
    int nxChunk = nx / 512;                // 16

    // workspace layout (every buffer fully written before read, every launch)
    char* w = (char*)d_ws;
    double* Tpart   = (double*)(w + 0);        // 512*8    = 4096          -> 4096
    double* partial = (double*)(w + 4096);     // 2112*8   = 16896         -> 20992
    float*  Spart   = (float*) (w + 20992);    // 512*64*4 = 131072        -> 152064
    float*  sq      = (float*) (w + 152064);   // N*4      = 65536         -> 217600
    float*  cq      = (float*) (w + 217600);   // 64 B pad                 -> 217664
    _Float16* zh    = (_Float16*)(w + 217664); // N*64*2   = 2 MiB

    k_pre   <<<pre_blocks, 256, 0, stream>>>(x, y, nx, zh, sq, Tpart, Spart);
    k_bw    <<<1, 256, 0, stream>>>(Tpart, pre_blocks, Spart, pre_blocks, N, cq);
    k_mmd   <<<nb, 256, 0, stream>>>(zh, sq, cq, nb, partial);
    k_final <<<1, 256, 0, stream>>>(partial, nb, nxTile, nxChunk, nx, ny, out);
}

// Round 13
// 127.198 us; speedup vs baseline: 2.8714x; 1.0141x over previous
//
#include <hip/hip_runtime.h>
#include <hip/hip_bf16.h>

#define D 64

typedef __attribute__((ext_vector_type(8))) _Float16 half8;
typedef __attribute__((ext_vector_type(4))) float floatx4;
typedef __attribute__((ext_vector_type(2))) float f32x2;

typedef __attribute__((address_space(1))) unsigned int gu32_t;
typedef __attribute__((address_space(3))) unsigned int lu32_t;

// ---- k_pre: fp16 convert + per-row sq + block partial sum(z^2) + block column sums ----
__global__ __launch_bounds__(256) void k_pre(const float* __restrict__ x, const float* __restrict__ y,
                                             int nx, _Float16* __restrict__ zh,
                                             float* __restrict__ sq, double* __restrict__ Tpart,
                                             float* __restrict__ Spart) {
    int tid = threadIdx.x;
    int lane = tid & 63, wid = tid >> 6;
    int t = blockIdx.x * 256 + tid;             // 8 elements per thread; block = 32 rows
    size_t e = (size_t)t * 8;
    int row = (int)(e >> 6);
    const float* src = (row < nx) ? (x + e) : (y + (e - (size_t)nx * D));
    float4 v0 = ((const float4*)src)[0];
    float4 v1 = ((const float4*)src)[1];
    half8 h;
    h[0]=(_Float16)v0.x; h[1]=(_Float16)v0.y; h[2]=(_Float16)v0.z; h[3]=(_Float16)v0.w;
    h[4]=(_Float16)v1.x; h[5]=(_Float16)v1.y; h[6]=(_Float16)v1.z; h[7]=(_Float16)v1.w;
    *(half8*)(zh + e) = h;
    float p = v0.x*v0.x + v0.y*v0.y + v0.z*v0.z + v0.w*v0.w
            + v1.x*v1.x + v1.y*v1.y + v1.z*v1.z + v1.w*v1.w;
    float s = p;
    s += __shfl_xor(s, 1);
    s += __shfl_xor(s, 2);
    s += __shfl_xor(s, 4);
    if ((tid & 7) == 0) sq[row] = s;

    __shared__ float colbuf[32][64];
    int rib = tid >> 3, cg = tid & 7;
    *(float4*)&colbuf[rib][cg * 8]     = v0;
    *(float4*)&colbuf[rib][cg * 8 + 4] = v1;

    double dp = (double)p;
    dp += __shfl_xor(dp, 1);
    dp += __shfl_xor(dp, 2);
    dp += __shfl_xor(dp, 4);
    dp += __shfl_xor(dp, 8);
    dp += __shfl_xor(dp, 16);
    dp += __shfl_xor(dp, 32);
    __shared__ double redw[4];
    if (lane == 0) redw[wid] = dp;
    __syncthreads();
    if (tid == 0) Tpart[blockIdx.x] = (redw[0] + redw[1]) + (redw[2] + redw[3]);

    if (tid < 64) {
        float cs = 0.f;
#pragma unroll
        for (int r2 = 0; r2 < 32; ++r2) cs += colbuf[r2][tid];
        Spart[blockIdx.x * 64 + tid] = cs;
    }
}

// ---- k_bw: reduce Tpart/Spart -> cq = log2e/(4*bw) ----
__global__ __launch_bounds__(256) void k_bw(const double* __restrict__ Tpart, int ntp,
                                            const float* __restrict__ Spart, int nsp,
                                            int N, float* __restrict__ cq_p) {
    int t = threadIdx.x;
    double Tp = 0.0;
    for (int b = t; b < ntp; b += 256) Tp += Tpart[b];

    int q = t >> 6, col = t & 63;
    int bpq = nsp >> 2;
    const float* sp = Spart + (size_t)(q * bpq) * 64 + col;
    float c0 = 0.f, c1 = 0.f, c2 = 0.f, c3 = 0.f;
    for (int b = 0; b < bpq; b += 4) {
        c0 += sp[(b + 0) * 64];
        c1 += sp[(b + 1) * 64];
        c2 += sp[(b + 2) * 64];
        c3 += sp[(b + 3) * 64];
    }
    __shared__ float cred[256];
    cred[t] = (c0 + c1) + (c2 + c3);

    __shared__ double red[256];
    red[t] = Tp;
    __syncthreads();
    for (int off = 128; off > 0; off >>= 1) {
        if (t < off) red[t] += red[t + off];
        __syncthreads();
    }
    double T = red[0];
    __shared__ double red2[64];
    if (t < 64) {
        float Sk = cred[t] + cred[t + 64] + cred[t + 128] + cred[t + 192];
        red2[t] = (double)Sk * (double)Sk;
    }
    __syncthreads();
    if (t == 0) {
        double S2 = 0.0;
        for (int i = 0; i < 64; ++i) S2 += red2[i];
        double sumd2 = 2.0 * (double)N * T - 2.0 * S2;
        double bw = sumd2 / ((double)N * (double)N - (double)N);
        cq_p[0] = (float)(1.4426950408889634 / (4.0 * bw));
    }
}

// ---- k_mmd: triangle pass, 64-j LDS tiles (global_load_lds + XOR swizzle),
//      f32x2 vector epilogue (compiler-emitted v_pk_*), clamp RESTORED ----
// LDS tile = 64 j-rows x 64 cols fp16 = 8KB, double-buffered. Swizzle: stored chunk cc holds
// source chunk cc ^ (row&7); achieved by pre-swizzled GLOBAL source + swizzled LDS read (m173).
__global__ __launch_bounds__(256, 6) void k_mmd(const _Float16* __restrict__ zh,
                                                const float* __restrict__ sq,
                                                const float* __restrict__ cq_p,
                                                int nb, double* __restrict__ partial) {
    int bid = (nb - 1) - (int)blockIdx.x;       // longest blocks first
    int g = (int)((sqrtf(1.0f + 2.0f * (float)bid) - 1.0f) * 0.5f);
    while (2 * (g + 1) * (g + 2) <= bid) ++g;
    while (2 * g * (g + 1) > bid) --g;
    int r = bid - 2 * g * (g + 1);
    int gp1 = g + 1;
    int rig = r / gp1;
    int jc  = r - rig * gp1;
    int ib  = 4 * g + rig;

    int jstart = jc * 512;
    int jend   = (ib + 1) * 128;
    if (jend > jstart + 512) jend = jstart + 512;
    int nt = (jend - jstart) >> 6;              // 64-j tiles: nt in {2,4,6,8}
    int diag_j = ib * 128;

    int tid  = threadIdx.x;
    int lane = tid & 63;
    int wid  = tid >> 6;
    int i0 = ib * 128 + wid * 32;

    float cq  = cq_p[0];
    f32x2 c2q2 = {2.0f * cq, 2.0f * cq};

    int lrow = lane & 15;
    int c2   = lane >> 4;                       // chunk index 0..3 (k-base = c2*8)
    int kb   = c2 * 8;

    // A fragments (once per block)
    const _Float16* ar0 = zh + (size_t)(i0 + lrow) * D + kb;
    half8 a00 = *(const half8*)(ar0);
    half8 a01 = *(const half8*)(ar0 + 32);
    half8 a10 = *(const half8*)(ar0 + 16 * D);
    half8 a11 = *(const half8*)(ar0 + 16 * D + 32);

    int irh = c2 * 4;
    f32x2 na[4];
    na[0] = (f32x2){-sq[i0 + irh + 0] * cq, -sq[i0 + irh + 1] * cq};
    na[1] = (f32x2){-sq[i0 + irh + 2] * cq, -sq[i0 + irh + 3] * cq};
    na[2] = (f32x2){-sq[i0 + 16 + irh + 0] * cq, -sq[i0 + 16 + irh + 1] * cq};
    na[3] = (f32x2){-sq[i0 + 16 + irh + 2] * cq, -sq[i0 + 16 + irh + 3] * cq};

    // ---- LDS staging setup (64-row tiles, 2 gload_lds per thread per tile) ----
    __shared__ __align__(16) _Float16 bsm[2][64 * 64];   // 2 x 8KB
    int srow = tid >> 3;                        // row 0..31 (+32 for second half)
    int scc  = tid & 7;                         // stored chunk slot 0..7
    int sc   = scc ^ (srow & 7);                // source chunk (involution; (row+32)&7 == row&7)
    const char* zbase = (const char*)zh + (size_t)jstart * 128 + srow * 128 + sc * 16;
    char* ldsw = (char*)&bsm[0][0] + wid * 1024;   // wave-uniform dest base

    auto STAGE = [&](int buf, int tile) {
        const char* src = zbase + (size_t)tile * (64 * 128);
        char* dst = ldsw + buf * 8192;
        __builtin_amdgcn_global_load_lds((const gu32_t*)(const void*)src,
                                         (lu32_t*)(void*)dst, 16, 0, 0);
        __builtin_amdgcn_global_load_lds((const gu32_t*)(const void*)(src + 32 * 128),
                                         (lu32_t*)(void*)(dst + 4096), 16, 0, 0);
    };

    float acc = 0.f;

    STAGE(0, 0);
    __syncthreads();                            // drain vmcnt(0) + barrier: buf0 ready

    for (int t = 0; t < nt; ++t) {
        if (t + 1 < nt) STAGE((t + 1) & 1, t + 1);   // issue next tile early
        const char* bb = (const char*)&bsm[t & 1][0];
        int j0t = jstart + t * 64;
#pragma unroll
        for (int s = 0; s < 4; ++s) {
            int jr = s * 16 + lrow;
            int swz = jr & 7;
            half8 b0 = *(const half8*)(bb + jr * 128 + ((c2 ^ swz) * 16));
            half8 b1 = *(const half8*)(bb + jr * 128 + (((c2 + 4) ^ swz) * 16));
            float sqj = sq[j0t + s * 16 + lrow];

            floatx4 d0 = {0.f, 0.f, 0.f, 0.f};
            floatx4 d1 = {0.f, 0.f, 0.f, 0.f};
            d0 = __builtin_amdgcn_mfma_f32_16x16x32_f16(a00, b0, d0, 0, 0, 0);
            d0 = __builtin_amdgcn_mfma_f32_16x16x32_f16(a01, b1, d0, 0, 0, 0);
            d1 = __builtin_amdgcn_mfma_f32_16x16x32_f16(a10, b0, d1, 0, 0, 0);
            d1 = __builtin_amdgcn_mfma_f32_16x16x32_f16(a11, b1, d1, 0, 0, 0);

            float nbj = -sqj * cq;
            f32x2 nb2 = {nbj, nbj};

            f32x2 dd[4];
            dd[0] = (f32x2){d0[0], d0[1]};
            dd[1] = (f32x2){d0[2], d0[3]};
            dd[2] = (f32x2){d1[0], d1[1]};
            dd[3] = (f32x2){d1[2], d1[3]};

            f32x2 part2 = {0.f, 0.f};
#pragma unroll
            for (int pk = 0; pk < 4; ++pk) {
                f32x2 u = dd[pk] * c2q2 + (na[pk] + nb2);   // v_pk_fma + v_pk_add
                u.x = fminf(u.x, 0.f);                      // clamp (scalar v_min x2)
                u.y = fminf(u.y, 0.f);
                f32x2 q;
                q.x = __builtin_amdgcn_exp2f(u.x);
                q.y = __builtin_amdgcn_exp2f(u.y);
                f32x2 m1 = q * q;                           // Eq^2
                f32x2 m2 = m1 * m1;                         // Eq^4
                f32x2 m3 = m2 * m2;                         // Eq^8
                part2 += ((q + m1) + (m2 + m3)) + m3 * m3;  // + Eq^16
            }
            float wf = ((j0t + s * 16) >= diag_j) ? 1.0f : 2.0f;
            acc = fmaf(part2.x + part2.y, wf, acc);
        }
        __syncthreads();                        // drain (next tile landed) + protect buffer reuse
    }

    // wave reduce (f64), then tiny LDS combine across the 4 waves
    double wacc = (double)acc;
    wacc += __shfl_xor(wacc, 1);
    wacc += __shfl_xor(wacc, 2);
    wacc += __shfl_xor(wacc, 4);
    wacc += __shfl_xor(wacc, 8);
    wacc += __shfl_xor(wacc, 16);
    wacc += __shfl_xor(wacc, 32);
    __shared__ double redr[4];
    if (lane == 0) redr[wid] = wacc;
    __syncthreads();
    if (tid == 0) partial[bid] = (redr[0] + redr[1]) + (redr[2] + redr[3]);
}

// ---- k_final: classify weighted partials into XX/XY/YY, finalize ----
__global__ __launch_bounds__(256) void k_final(const double* __restrict__ partial, int nb,
                                               int nxTile, int nxChunk,
                                               int nx, int ny, float* __restrict__ out) {
    int t = threadIdx.x;
    double sXX = 0.0, sXY = 0.0, sYY = 0.0;
    for (int p = t; p < nb; p += 256) {
        int g = (int)((sqrtf(1.0f + 2.0f * (float)p) - 1.0f) * 0.5f);
        while (2 * (g + 1) * (g + 2) <= p) ++g;
        while (2 * g * (g + 1) > p) --g;
        int r = p - 2 * g * (g + 1);
        int gp1 = g + 1;
        int rig = r / gp1;
        int jc  = r - rig * gp1;
        int ib  = 4 * g + rig;
        double v = partial[p];
        bool iX = ib < nxTile;
        bool jX = jc < nxChunk;
        if (iX && jX) sXX += v;
        else if (iX != jX) sXY += v;
        else sYY += v;
    }
    __shared__ double r0[256], r1[256], r2[256];
    r0[t] = sXX; r1[t] = sXY; r2[t] = sYY;
    __syncthreads();
    for (int off = 128; off > 0; off >>= 1) {
        if (t < off) {
            r0[t] += r0[t + off];
            r1[t] += r1[t + off];
            r2[t] += r2[t + off];
        }
        __syncthreads();
    }
    if (t == 0) {
        double XX = r0[0] / ((double)nx * (double)nx);
        double XY = r1[0] / (2.0 * (double)nx * (double)ny);
        double YY = r2[0] / ((double)ny * (double)ny);
        out[0] = (float)(XX - 2.0 * XY + YY);
    }
}

extern "C" void kernel_launch(void* const* d_in, const int* in_sizes, int n_in,
                              void* d_out, int out_size, void* d_ws, size_t ws_size,
                              hipStream_t stream) {
    const float* x = (const float*)d_in[0];
    const float* y = (const float*)d_in[1];
    float* out = (float*)d_out;

    int nx = in_sizes[0] / D;     // 8192
    int ny = in_sizes[1] / D;     // 8192
    int N  = nx + ny;             // 16384

    int pre_blocks = (N * D / 8) / 256;    // 512 (32 rows per block)
    int nT = N / 128;                      // 128 i-tiles
    int ngr = nT / 4;                      // 32 row groups
    int nb = 2 * ngr * (ngr + 1);          // 2112 triangle chunk-blocks
    int nxTile = nx / 128;                 // 64
    int nxChunk = nx / 512;                // 16

    // workspace layout (every buffer fully written before read, every launch)
    char* w = (char*)d_ws;
    double* Tpart   = (double*)(w + 0);        // 512*8    = 4096          -> 4096
    double* partial = (double*)(w + 4096);     // 2112*8   = 16896         -> 20992
    float*  Spart   = (float*) (w + 20992);    // 512*64*4 = 131072        -> 152064
    float*  sq      = (float*) (w + 152064);   // N*4      = 65536         -> 217600
    float*  cq      = (float*) (w + 217600);   // 64 B pad                 -> 217664
    _Float16* zh    = (_Float16*)(w + 217664); // N*64*2   = 2 MiB

    k_pre   <<<pre_blocks, 256, 0, stream>>>(x, y, nx, zh, sq, Tpart, Spart);
    k_bw    <<<1, 256, 0, stream>>>(Tpart, pre_blocks, Spart, pre_blocks, N, cq);
    k_mmd   <<<nb, 256, 0, stream>>>(zh, sq, cq, nb, partial);
    k_final <<<1, 256, 0, stream>>>(partial, nb, nxTile, nxChunk, nx, ny, out);
}